// Round 7
// baseline (354.273 us; speedup 1.0000x reference)
//
#include <hip/hip_runtime.h>
#include <hip/hip_bf16.h>

// Problem constants
#define BB 16
#define NN 1024
#define CC 768
#define HH 12
#define DH 64
#define NSC 196
#define N1 1220              // NN + NSC
#define MPAD 19712           // 77*256, padded row count of xt (256-tile GEMM)
#define M_QKV (BB * N1)      // 19520 (valid rows)
#define N_QKV (3 * CC)       // 2304
#define M_PROJ (BB * NN)     // 16384
#define KP 1232              // VT padded key count; 192*64*KP*2 B == MPAD*CC*2 B exactly

typedef __attribute__((ext_vector_type(8))) short short8;   // 8 bf16 = 4 VGPRs
typedef __attribute__((ext_vector_type(4))) float f32x4;

#define SC2F 0.125f   // softmax scale folded into Q; softmax uses native __expf

__device__ __forceinline__ void load_lds16(const void* g, void* l) {
    __builtin_amdgcn_global_load_lds(
        (__attribute__((address_space(1))) void*)(g),
        (__attribute__((address_space(3))) void*)(l),
        16, 0, 0);
}

// ---------------------------------------------------------------------------
// Cast kernels (one-time): build bf16 xt (concat + zero-pad) and transposed
// bf16 weights so GEMM B operand is row-major [n][k].
// ---------------------------------------------------------------------------
__global__ __launch_bounds__(256) void cast_xt_kernel(
    const float* __restrict__ x, const float* __restrict__ sct,
    __hip_bfloat16* __restrict__ xt)
{
    const int e   = blockIdx.x * 256 + threadIdx.x;   // MPAD*96 threads
    const int row = e / 96;
    const int c8  = (e - row * 96) * 8;
    union { short8 s; __hip_bfloat16 h[8]; } u;
    if (row < M_QKV) {
        const int b  = row / N1;
        const int rr = row - b * N1;
        const float* src = (rr < NN)
            ? x   + ((size_t)b * NN + rr) * CC + c8
            : sct + (size_t)(rr - NN) * CC + c8;
        const float4 v0 = *(const float4*)src;
        const float4 v1 = *(const float4*)(src + 4);
        u.h[0] = __float2bfloat16(v0.x); u.h[1] = __float2bfloat16(v0.y);
        u.h[2] = __float2bfloat16(v0.z); u.h[3] = __float2bfloat16(v0.w);
        u.h[4] = __float2bfloat16(v1.x); u.h[5] = __float2bfloat16(v1.y);
        u.h[6] = __float2bfloat16(v1.z); u.h[7] = __float2bfloat16(v1.w);
    } else {
#pragma unroll
        for (int j = 0; j < 8; ++j) u.h[j] = __float2bfloat16(0.f);
    }
    *(short8*)(xt + (size_t)row * CC + c8) = u.s;
}

// W: [K=768][Ncols] fp32 -> WT: [Ncols][768] bf16
__global__ __launch_bounds__(256) void cast_wt_kernel(
    const float* __restrict__ W, __hip_bfloat16* __restrict__ WT, int Ncols)
{
    const int e  = blockIdx.x * 256 + threadIdx.x;    // Ncols*96 threads
    const int n  = e / 96;
    const int k8 = (e - n * 96) * 8;
    union { short8 s; __hip_bfloat16 h[8]; } u;
#pragma unroll
    for (int j = 0; j < 8; ++j)
        u.h[j] = __float2bfloat16(W[(size_t)(k8 + j) * Ncols + n]);
    *(short8*)(WT + (size_t)n * CC + k8) = u.s;
}

// ---------------------------------------------------------------------------
// One-time V transpose: qkv V-columns [key][d] -> VT [b][h][d][KP keys] bf16.
// Keys in [N1, KP) are zeroed. Grid (20, HH, BB).
// ---------------------------------------------------------------------------
__global__ __launch_bounds__(256) void transpose_v_kernel(
    const __hip_bfloat16* __restrict__ qkv, __hip_bfloat16* __restrict__ vt)
{
    __shared__ short Ls[64 * 72];
    const int t  = threadIdx.x;
    const int kt = blockIdx.x, h = blockIdx.y, b = blockIdx.z;
    const __hip_bfloat16* vb = qkv + (size_t)b * N1 * N_QKV + 2 * CC + h * DH;

#pragma unroll
    for (int i = 0; i < 2; ++i) {
        const int c   = t + 256 * i;          // 512 chunks of 16B = 8KB tile
        const int key = c >> 3;
        const int d8  = (c & 7) * 8;
        const int kg  = kt * 64 + key;
        union { short8 s; short hh[8]; } u;
        if (kg < N1) {
            u.s = *(const short8*)(vb + (size_t)kg * N_QKV + d8);
        } else {
#pragma unroll
            for (int j = 0; j < 8; ++j) u.hh[j] = 0;
        }
#pragma unroll
        for (int j = 0; j < 8; ++j) Ls[(d8 + j) * 72 + key] = u.hh[j];
    }
    __syncthreads();
    __hip_bfloat16* ob = vt + (size_t)(b * HH + h) * 64 * KP + kt * 64;
#pragma unroll
    for (int i = 0; i < 2; ++i) {
        const int c  = t + 256 * i;
        const int d  = c >> 3;
        const int k8 = (c & 7) * 8;
        if (kt * 64 + k8 + 8 <= KP)
            *(short8*)(ob + (size_t)d * KP + k8) = *(const short8*)&Ls[d * 72 + k8];
    }
}

// ---------------------------------------------------------------------------
// 8-phase 256x256 MFMA GEMM (m201 template, parameterized to K=768).
// C = A . BT^T. 512 threads = 8 waves (2M x 4N), each wave owns 128x64 of C.
// K-tile = 64; 4 phases per K-tile, each phase = {ds_read one C-quadrant's
// frags (+ B frags at phase 0) | stage 1 half-tile into the other region |
// barrier | 16 MFMA (setprio) | counted vmcnt at phase 3 | barrier}.
// LDS 128 KB: As/Bs[2 dbuf][2 half][128][64], dbuf = kt&1.
// Stage->consume schedule: A(kt+1) staged kt phases 0-1 (opposite dbuf,
// free since kt-1 end); B(kt+2) staged kt phases 2-3 (same dbuf as current
// B, whose reads all complete in phase 0). vmcnt(4) at kt phase-3-end
// guarantees A(kt+1)+B(kt+1) landed; B(kt+2)'s 4 loads stay in flight.
// Both-sides XOR swizzle (16B unit ^= row&7, pre-swizzled source) -> all
// ds_read_b128 conflict-free. Bijective XCD swizzle (m204).
// ---------------------------------------------------------------------------
template <bool WRITE_BF16, bool QSCALE>
__global__ __launch_bounds__(512, 1) void gemm8p(
    const __hip_bfloat16* __restrict__ A,
    const __hip_bfloat16* __restrict__ BT,
    void* __restrict__ Cout,
    const float* __restrict__ bias,
    int lda, int K, int ldc, int Mvalid)
{
    __shared__ __hip_bfloat16 As[2 * 2 * 128 * 64];   // 64 KB
    __shared__ __hip_bfloat16 Bs[2 * 2 * 128 * 64];   // 64 KB

    const int t    = threadIdx.x;
    const int l15  = t & 15;
    const int quad = (t >> 4) & 3;
    const int w    = t >> 6;
    const int wm   = w >> 2;          // 0..1 -> rows wm*128..+128
    const int wn   = w & 3;           // 0..3 -> cols wn*64..+64
    const int swz  = l15 & 7;

    // bijective XCD swizzle (m204)
    const int nwg = gridDim.x * gridDim.y;
    const int lin = blockIdx.y * gridDim.x + blockIdx.x;
    const int qq  = nwg >> 3, rr = nwg & 7;
    const int xcd = lin & 7, off = lin >> 3;
    const int sw  = ((xcd < rr) ? xcd * (qq + 1)
                                : rr * (qq + 1) + (xcd - rr) * qq) + off;
    const int n0 = (sw % gridDim.x) * 256;
    const int m0 = (sw / gridDim.x) * 256;

    // Staging: half-tile = 128 rows x 64 k = 16 KB = 512 thr x 2 chunks x 16B.
    // Thread t covers chunks t and t+512: rows r0 and r0+64, same swizzled
    // source unit su (rows differ by 64 -> row&7 equal).
    const int r0 = t >> 3;                        // 0..63
    const int su = ((t & 7) ^ (r0 & 7)) * 8;      // pre-swizzled k-offset (elems)

    const __hip_bfloat16* gA = A  + (size_t)(m0 + r0) * lda + su;
    const __hip_bfloat16* gB = BT + (size_t)(n0 + r0) * K   + su;

#define SA(kt_, half_) do {                                                     \
        __hip_bfloat16* _l = As + (((kt_) & 1) * 2 + (half_)) * 8192 + t * 8;   \
        const __hip_bfloat16* _g = gA + (size_t)((half_) * 128) * lda + (kt_) * 64; \
        load_lds16(_g, _l);                                                     \
        load_lds16(_g + (size_t)64 * lda, _l + 4096);                           \
    } while (0)
#define SB(kt_, half_) do {                                                     \
        __hip_bfloat16* _l = Bs + (((kt_) & 1) * 2 + (half_)) * 8192 + t * 8;   \
        const __hip_bfloat16* _g = gB + (size_t)((half_) * 128) * K + (kt_) * 64; \
        load_lds16(_g, _l);                                                     \
        load_lds16(_g + (size_t)64 * K, _l + 4096);                             \
    } while (0)

    f32x4 acc[8][4];
#pragma unroll
    for (int mi = 0; mi < 8; ++mi)
#pragma unroll
        for (int ni = 0; ni < 4; ++ni) {
            acc[mi][ni][0] = 0.f; acc[mi][ni][1] = 0.f;
            acc[mi][ni][2] = 0.f; acc[mi][ni][3] = 0.f;
        }

    // Prologue: A(0) both halves, B(0) both halves, B(1) both halves.
    // vmcnt(4): A0+B0 (8 loads) landed; B1's 4 loads stay in flight.
    SA(0, 0); SA(0, 1); SB(0, 0); SB(0, 1); SB(1, 0); SB(1, 1);
    asm volatile("s_waitcnt vmcnt(4)" ::: "memory");
    __builtin_amdgcn_s_barrier();
    __builtin_amdgcn_sched_barrier(0);

    const int NT = K >> 6;            // 12 K-tiles at K=768
    const int brow = (wn & 1) * 64;   // wave's row base within its B half
    for (int kt = 0; kt < NT; ++kt) {
        const int d = kt & 1;
        const __hip_bfloat16* Ab = As + (d * 2 + wm) * 8192;
        const __hip_bfloat16* Bb = Bs + (d * 2 + (wn >> 1)) * 8192;
        short8 bf[4][2];

#pragma unroll
        for (int q = 0; q < 4; ++q) {
            short8 af[2][2];
#pragma unroll
            for (int dmi = 0; dmi < 2; ++dmi)
#pragma unroll
                for (int ks = 0; ks < 2; ++ks)
                    af[dmi][ks] = *(const short8*)
                        &Ab[(q * 32 + dmi * 16 + l15) * 64 + (((ks * 4 + quad) ^ swz) << 3)];
            if (q == 0) {
#pragma unroll
                for (int ni = 0; ni < 4; ++ni)
#pragma unroll
                    for (int ks = 0; ks < 2; ++ks)
                        bf[ni][ks] = *(const short8*)
                            &Bb[(brow + ni * 16 + l15) * 64 + (((ks * 4 + quad) ^ swz) << 3)];
            }
            // stage one half-tile per phase (uniform conditions -> no divergence)
            if (q == 0 && kt + 1 < NT) SA(kt + 1, 0);
            if (q == 1 && kt + 1 < NT) SA(kt + 1, 1);
            if (q == 2 && kt + 2 < NT) SB(kt + 2, 0);
            if (q == 3 && kt + 2 < NT) SB(kt + 2, 1);

            __builtin_amdgcn_s_barrier();
            __builtin_amdgcn_sched_barrier(0);
            __builtin_amdgcn_s_setprio(1);
#pragma unroll
            for (int ks = 0; ks < 2; ++ks)
#pragma unroll
                for (int dmi = 0; dmi < 2; ++dmi)
#pragma unroll
                    for (int ni = 0; ni < 4; ++ni)
                        acc[q * 2 + dmi][ni] = __builtin_amdgcn_mfma_f32_16x16x32_bf16(
                            af[dmi][ks], bf[ni][ks], acc[q * 2 + dmi][ni], 0, 0, 0);
            __builtin_amdgcn_s_setprio(0);

            if (q == 3) {
                if (kt + 2 < NT)      asm volatile("s_waitcnt vmcnt(4)" ::: "memory");
                else if (kt + 1 < NT) asm volatile("s_waitcnt vmcnt(0)" ::: "memory");
            }
            __builtin_amdgcn_s_barrier();
            __builtin_amdgcn_sched_barrier(0);
        }
    }
#undef SA
#undef SB

    // Epilogue (R2-verified). C/D layout: col = l15, row = quad*4 + reg.
#pragma unroll
    for (int mi = 0; mi < 8; ++mi) {
        const int rowb = m0 + wm * 128 + mi * 16 + quad * 4;
#pragma unroll
        for (int ni = 0; ni < 4; ++ni) {
            const int col = n0 + wn * 64 + ni * 16 + l15;
#pragma unroll
            for (int r = 0; r < 4; ++r) {
                const int row = rowb + r;
                if (row < Mvalid) {
                    float v = acc[mi][ni][r];
                    if (WRITE_BF16) {
                        if (QSCALE && n0 < CC) v *= SC2F;   // fold softmax scale into Q
                        ((__hip_bfloat16*)Cout)[(size_t)row * ldc + col] = __float2bfloat16(v);
                    } else {
                        ((float*)Cout)[(size_t)row * ldc + col] = v + bias[col];
                    }
                }
            }
        }
    }
}

// ---------------------------------------------------------------------------
// Flash attention (R6-proven): Ks single-buffered + mid-barrier, Vs double-
// buffered; staging issued after QK^T so latency hides under softmax+PV.
// Max-free softmax via native __expf; conflict-free XOR-swizzled LDS;
// per-wave P tile; setprio; XCD swizzle for K/V L2 residency.
// ---------------------------------------------------------------------------
__global__ __launch_bounds__(256, 4) void attn_mfma_kernel(
    const __hip_bfloat16* qkv,
    const __hip_bfloat16* __restrict__ vt,
    __hip_bfloat16* ao)                  // = qkv + 2*CC (V-column base)
{
    __shared__ __hip_bfloat16 Ks[64 * 64];      // 8 KB, single
    __shared__ __hip_bfloat16 Vs[2][64 * 64];   // 16 KB, double
    __shared__ short Pl[4 * 16 * 64];           // 8 KB, per-wave

    const int t    = threadIdx.x;
    const int l15  = t & 15;
    const int quad = (t >> 4) & 3;
    const int w    = t >> 6;
    const int swz  = l15 & 7;

    // XCD swizzle: each XCD owns 24 (b,h) pairs with all 16 q-tiles
    const int L    = blockIdx.x + 16 * (blockIdx.y + 12 * blockIdx.z);
    const int g    = L & 7, s = L >> 3;
    const int pair = g * 24 + (s >> 4);
    const int qt   = s & 15;
    const int h    = pair % 12;
    const int b    = pair / 12;

    const size_t rowbase = (size_t)b * N1;
    const __hip_bfloat16* qb  = qkv + rowbase * N_QKV + h * DH;
    const __hip_bfloat16* kb  = qkv + rowbase * N_QKV + CC + h * DH;
    const __hip_bfloat16* vtb = vt + (size_t)(b * HH + h) * 64 * KP;

    const int cA = t,       rA = cA >> 3, uA = (cA & 7) ^ (rA & 7);
    const int cB = t + 256, rB = cB >> 3, uB = (cB & 7) ^ (rB & 7);

#define KSTAGE(k0) do {                                                            \
        load_lds16(kb + (size_t)((k0) + rA) * N_QKV + uA * 8, (char*)Ks + cA * 16); \
        load_lds16(kb + (size_t)((k0) + rB) * N_QKV + uB * 8, (char*)Ks + cB * 16); \
    } while (0)
#define VSTAGE(bi, k0) do {                                                        \
        load_lds16(vtb + (size_t)rA * KP + (k0) + uA * 8, (char*)&Vs[(bi)][0] + cA * 16); \
        load_lds16(vtb + (size_t)rB * KP + (k0) + uB * 8, (char*)&Vs[(bi)][0] + cB * 16); \
    } while (0)

    short8 qf[2];
    {
        const size_t qrow = (size_t)(qt * 64 + w * 16 + l15);
#pragma unroll
        for (int ks = 0; ks < 2; ++ks)
            qf[ks] = *(const short8*)(qb + qrow * N_QKV + ks * 32 + quad * 8);
    }

    f32x4 oac[4];
#pragma unroll
    for (int dt = 0; dt < 4; ++dt) {
        oac[dt][0] = 0.f; oac[dt][1] = 0.f; oac[dt][2] = 0.f; oac[dt][3] = 0.f;
    }
    float lrun = 0.f;
    short* Pw = Pl + (w * 16) * 64;

    // prologue: stage tile 0 (K and V), drain, barrier
    KSTAGE(0);
    VSTAGE(0, 0);
    __syncthreads();

    int cur = 0;
    for (int k0 = 0; k0 < N1; k0 += 64) {
        // ---- read K fragments to regs, QK^T (register-only) ----
        short8 kf[4][2];
#pragma unroll
        for (int mt = 0; mt < 4; ++mt)
#pragma unroll
            for (int ks = 0; ks < 2; ++ks)
                kf[mt][ks] = *(const short8*)
                    &Ks[(mt * 16 + l15) * 64 + ((4 * ks + quad) ^ swz) * 8];

        f32x4 st[4];
#pragma unroll
        for (int mt = 0; mt < 4; ++mt) {
            st[mt][0] = 0.f; st[mt][1] = 0.f; st[mt][2] = 0.f; st[mt][3] = 0.f;
        }
        __builtin_amdgcn_s_setprio(1);
#pragma unroll
        for (int ks = 0; ks < 2; ++ks)
#pragma unroll
            for (int mt = 0; mt < 4; ++mt)
                st[mt] = __builtin_amdgcn_mfma_f32_16x16x32_bf16(
                    kf[mt][ks], qf[ks], st[mt], 0, 0, 0);
        __builtin_amdgcn_s_setprio(0);

        // ---- mid-barrier: all waves done reading Ks (no vmem outstanding) ----
        __syncthreads();

        // ---- issue next tile's staging; latency hides under softmax+PV ----
        if (k0 + 64 < N1) {
            KSTAGE(k0 + 64);
            VSTAGE(cur ^ 1, k0 + 64);
        }

        // ---- max-free softmax: scale folded into Q, exp args bounded ----
        if (k0 + 64 > N1) {              // mask padded keys (last iter only)
#pragma unroll
            for (int mt = 0; mt < 4; ++mt)
#pragma unroll
                for (int r = 0; r < 4; ++r)
                    if (k0 + mt * 16 + quad * 4 + r >= N1) st[mt][r] = -1e30f;
        }
        float rsum = 0.f;
#pragma unroll
        for (int mt = 0; mt < 4; ++mt)
#pragma unroll
            for (int r = 0; r < 4; ++r) {
                const float p = __expf(st[mt][r]);
                st[mt][r] = p;
                rsum += p;
            }
        rsum += __shfl_xor(rsum, 16);
        rsum += __shfl_xor(rsum, 32);
        lrun += rsum;

        // P -> per-wave swizzled LDS tile (8B writes, conflict-free)
#pragma unroll
        for (int mt = 0; mt < 4; ++mt) {
            union { unsigned long long u; __hip_bfloat16 hh[4]; } pk;
#pragma unroll
            for (int r = 0; r < 4; ++r) pk.hh[r] = __float2bfloat16(st[mt][r]);
            const int unit = (2 * mt + (quad >> 1)) ^ swz;
            *(unsigned long long*)&Pw[l15 * 64 + unit * 8 + (quad & 1) * 4] = pk.u;
        }

        __builtin_amdgcn_s_setprio(1);
#pragma unroll
        for (int ks = 0; ks < 2; ++ks) {
            const short8 pf = *(const short8*)
                &Pw[l15 * 64 + ((4 * ks + quad) ^ swz) * 8];
#pragma unroll
            for (int dt = 0; dt < 4; ++dt) {
                const short8 vf = *(const short8*)
                    &Vs[cur][(l15 + 16 * dt) * 64 + ((4 * ks + quad) ^ swz) * 8];
                oac[dt] = __builtin_amdgcn_mfma_f32_16x16x32_bf16(pf, vf, oac[dt], 0, 0, 0);
            }
        }
        __builtin_amdgcn_s_setprio(0);

        // end barrier: drains my staging -> buffers sealed for next iter
        __syncthreads();
        cur ^= 1;
    }
#undef KSTAGE
#undef VSTAGE

    const float li = 1.0f / lrun;
#pragma unroll
    for (int r = 0; r < 4; ++r) {
        const float ir = __shfl(li, quad * 4 + r);
        const int qrow = qt * 64 + w * 16 + quad * 4 + r;
        __hip_bfloat16* orow = ao + ((size_t)b * NN + qrow) * N_QKV + h * DH;
#pragma unroll
        for (int dt = 0; dt < 4; ++dt)
            orow[l15 + 16 * dt] = __float2bfloat16(oac[dt][r] * ir);
    }
}

// ---------------------------------------------------------------------------
extern "C" void kernel_launch(void* const* d_in, const int* in_sizes, int n_in,
                              void* d_out, int out_size, void* d_ws, size_t ws_size,
                              hipStream_t stream) {
    const float* x      = (const float*)d_in[0];
    const float* sct    = (const float*)d_in[1];
    const float* W_qkv  = (const float*)d_in[2];
    const float* W_proj = (const float*)d_in[3];
    const float* b_proj = (const float*)d_in[4];
    float* out = (float*)d_out;

    // ws layout (bytes), total 124,944,384 (R2-verified footprint):
    //   [0, 30,277,632):   xt bf16 [19712][768]; later reused as VT bf16
    //                      [192*64][1232] (identical size)
    //   [.., +89,948,160): qkv bf16 [19520][2304]; attn out goes into the
    //                      dead V columns [1536..2304). attn's masked-key
    //                      staging may read a few KB past into the WT area
    //                      (finite bf16, values masked -> contributes 0).
    //   then WT_qkv bf16 [2304][768], WT_proj bf16 [768][768]
    char* p = (char*)d_ws;
    __hip_bfloat16* xt      = (__hip_bfloat16*)p;
    __hip_bfloat16* vtg     = (__hip_bfloat16*)p;            // aliases xt (dead)
    __hip_bfloat16* qkv     = (__hip_bfloat16*)(p + (size_t)MPAD * CC * 2);
    __hip_bfloat16* WTqkv   = (__hip_bfloat16*)(p + (size_t)MPAD * CC * 2 + (size_t)M_QKV * N_QKV * 2);
    __hip_bfloat16* WTproj  = WTqkv + (size_t)N_QKV * CC;
    __hip_bfloat16* ao      = qkv + 2 * CC;                  // attn out, stride N_QKV

    cast_xt_kernel<<<MPAD * 96 / 256, 256, 0, stream>>>(x, sct, xt);
    cast_wt_kernel<<<N_QKV * 96 / 256, 256, 0, stream>>>(W_qkv, WTqkv, N_QKV);
    cast_wt_kernel<<<CC * 96 / 256, 256, 0, stream>>>(W_proj, WTproj, CC);

    gemm8p<true, true><<<dim3(N_QKV / 256, MPAD / 256), 512, 0, stream>>>(
        xt, WTqkv, qkv, nullptr, CC, CC, N_QKV, M_QKV);
    transpose_v_kernel<<<dim3((N1 + 63) / 64, HH, BB), 256, 0, stream>>>(qkv, vtg);
    attn_mfma_kernel<<<dim3(NN / 64, HH, BB), 256, 0, stream>>>(qkv, vtg, ao);
    gemm8p<false, false><<<dim3(CC / 256, M_PROJ / 256), 512, 0, stream>>>(
        ao, WTproj, out, b_proj, N_QKV, CC, CC, M_PROJ);
}

// Round 8
// 339.449 us; speedup vs baseline: 1.0437x; 1.0437x over previous
//
#include <hip/hip_runtime.h>
#include <hip/hip_bf16.h>

// Problem constants
#define BB 16
#define NN 1024
#define CC 768
#define HH 12
#define DH 64
#define NSC 196
#define N1 1220              // NN + NSC
#define MPAD 19584           // 153*128, padded row count of xt
#define M_QKV (BB * N1)      // 19520 (valid rows)
#define N_QKV (3 * CC)       // 2304
#define M_PROJ (BB * NN)     // 16384
#define KP 1224              // VT padded key count; 192*64*KP*2 B == MPAD*CC*2 B exactly

#define XT_BLOCKS (MPAD * 96 / 256)    // 7344
#define WQ_BLOCKS (N_QKV * 96 / 256)   // 864
#define WP_BLOCKS (CC * 96 / 256)      // 288

typedef __attribute__((ext_vector_type(8))) short short8;   // 8 bf16 = 4 VGPRs
typedef __attribute__((ext_vector_type(4))) float f32x4;

#define SC2F 0.125f   // softmax scale folded into Q; softmax uses native __expf

__device__ __forceinline__ void load_lds16(const void* g, void* l) {
    __builtin_amdgcn_global_load_lds(
        (__attribute__((address_space(1))) void*)(g),
        (__attribute__((address_space(3))) void*)(l),
        16, 0, 0);
}

// ---------------------------------------------------------------------------
// Merged one-time cast kernel (single launch): block-range dispatch.
//   [0, XT_BLOCKS)                : bf16 xt (concat + zero-pad)
//   [XT_BLOCKS, +WQ_BLOCKS)       : W_qkv  -> WTqkv  [2304][768] bf16
//   [XT_BLOCKS+WQ_BLOCKS, +WP_..) : W_proj -> WTproj [768][768] bf16
// Branch is block-uniform -> no divergence.
// ---------------------------------------------------------------------------
__global__ __launch_bounds__(256) void cast_all_kernel(
    const float* __restrict__ x, const float* __restrict__ sct,
    const float* __restrict__ W_qkv, const float* __restrict__ W_proj,
    __hip_bfloat16* __restrict__ xt,
    __hip_bfloat16* __restrict__ WTqkv, __hip_bfloat16* __restrict__ WTproj)
{
    const int blk = blockIdx.x;
    if (blk < XT_BLOCKS) {
        const int e   = blk * 256 + threadIdx.x;
        const int row = e / 96;
        const int c8  = (e - row * 96) * 8;
        union { short8 s; __hip_bfloat16 h[8]; } u;
        if (row < M_QKV) {
            const int b  = row / N1;
            const int rr = row - b * N1;
            const float* src = (rr < NN)
                ? x   + ((size_t)b * NN + rr) * CC + c8
                : sct + (size_t)(rr - NN) * CC + c8;
            const float4 v0 = *(const float4*)src;
            const float4 v1 = *(const float4*)(src + 4);
            u.h[0] = __float2bfloat16(v0.x); u.h[1] = __float2bfloat16(v0.y);
            u.h[2] = __float2bfloat16(v0.z); u.h[3] = __float2bfloat16(v0.w);
            u.h[4] = __float2bfloat16(v1.x); u.h[5] = __float2bfloat16(v1.y);
            u.h[6] = __float2bfloat16(v1.z); u.h[7] = __float2bfloat16(v1.w);
        } else {
#pragma unroll
            for (int j = 0; j < 8; ++j) u.h[j] = __float2bfloat16(0.f);
        }
        *(short8*)(xt + (size_t)row * CC + c8) = u.s;
    } else {
        const float* W;
        __hip_bfloat16* WT;
        int base, Ncols;
        if (blk < XT_BLOCKS + WQ_BLOCKS) {
            W = W_qkv; WT = WTqkv; base = blk - XT_BLOCKS; Ncols = N_QKV;
        } else {
            W = W_proj; WT = WTproj; base = blk - XT_BLOCKS - WQ_BLOCKS; Ncols = CC;
        }
        const int e  = base * 256 + threadIdx.x;
        const int n  = e / 96;
        const int k8 = (e - n * 96) * 8;
        union { short8 s; __hip_bfloat16 h[8]; } u;
#pragma unroll
        for (int j = 0; j < 8; ++j)
            u.h[j] = __float2bfloat16(W[(size_t)(k8 + j) * Ncols + n]);
        *(short8*)(WT + (size_t)n * CC + k8) = u.s;
    }
}

// ---------------------------------------------------------------------------
// One-time V transpose: qkv V-columns [key][d] -> VT [b][h][d][KP keys] bf16.
// Keys in [N1, KP) are zeroed. Grid (20, HH, BB).
// ---------------------------------------------------------------------------
__global__ __launch_bounds__(256) void transpose_v_kernel(
    const __hip_bfloat16* __restrict__ qkv, __hip_bfloat16* __restrict__ vt)
{
    __shared__ short Ls[64 * 72];
    const int t  = threadIdx.x;
    const int kt = blockIdx.x, h = blockIdx.y, b = blockIdx.z;
    const __hip_bfloat16* vb = qkv + (size_t)b * N1 * N_QKV + 2 * CC + h * DH;

#pragma unroll
    for (int i = 0; i < 2; ++i) {
        const int c   = t + 256 * i;          // 512 chunks of 16B = 8KB tile
        const int key = c >> 3;
        const int d8  = (c & 7) * 8;
        const int kg  = kt * 64 + key;
        union { short8 s; short hh[8]; } u;
        if (kg < N1) {
            u.s = *(const short8*)(vb + (size_t)kg * N_QKV + d8);
        } else {
#pragma unroll
            for (int j = 0; j < 8; ++j) u.hh[j] = 0;
        }
#pragma unroll
        for (int j = 0; j < 8; ++j) Ls[(d8 + j) * 72 + key] = u.hh[j];
    }
    __syncthreads();
    __hip_bfloat16* ob = vt + (size_t)(b * HH + h) * 64 * KP + kt * 64;
#pragma unroll
    for (int i = 0; i < 2; ++i) {
        const int c  = t + 256 * i;
        const int d  = c >> 3;
        const int k8 = (c & 7) * 8;
        if (kt * 64 + k8 < KP)               // last k-tile only writes 8 keys/row
            *(short8*)(ob + (size_t)d * KP + k8) = *(const short8*)&Ls[d * 72 + k8];
    }
}

// ---------------------------------------------------------------------------
// MFMA GEMM, BK=64 (R6-proven, best at this shape): C = A . BT^T.
// 128x128 tile, 256 threads (4 waves, 64x64 each), global_load_lds width-16
// staging, 2-barrier loop -> 12 drains at K=768. Both-sides XOR swizzle
// (16B unit ^= row&7, pre-swizzled source) -> ds_read_b128 2-way (free).
// Bijective XCD swizzle (m204) keeps each XCD's A-panels L2-resident.
// ---------------------------------------------------------------------------
template <bool WRITE_BF16, bool QSCALE>
__global__ __launch_bounds__(256) void mfma_gemm_bt(
    const __hip_bfloat16* __restrict__ A,
    const __hip_bfloat16* __restrict__ BT,
    void* __restrict__ Cout,
    const float* __restrict__ bias,
    int lda, int K, int ldc)
{
    __shared__ __hip_bfloat16 As[128 * 64];   // 16 KB
    __shared__ __hip_bfloat16 Bs[128 * 64];   // 16 KB

    const int t    = threadIdx.x;
    const int lane = t & 63;
    const int l15  = lane & 15;
    const int quad = lane >> 4;
    const int w    = t >> 6;
    const int wm   = w & 1;
    const int wn   = w >> 1;
    const int swz  = l15 & 7;

    // bijective XCD swizzle (m204)
    const int nwg = gridDim.x * gridDim.y;
    const int lin = blockIdx.y * gridDim.x + blockIdx.x;
    const int qq  = nwg >> 3, rr = nwg & 7;
    const int xcd = lin & 7, off = lin >> 3;
    const int sw  = ((xcd < rr) ? xcd * (qq + 1)
                                : rr * (qq + 1) + (xcd - rr) * qq) + off;
    const int n0 = (sw % gridDim.x) * 128;
    const int m0 = (sw / gridDim.x) * 128;

    // Staging: thread t covers chunks c = t + 256*i (i=0..3), 16 B each.
    const int rr0 = t >> 3;                          // 0..31
    const int uu  = ((t & 7) ^ (rr0 & 7)) * 8;       // pre-swizzled source offset

    const __hip_bfloat16* gA = A  + (size_t)(m0 + rr0) * lda + uu;
    const __hip_bfloat16* gB = BT + (size_t)(n0 + rr0) * K   + uu;
    __hip_bfloat16* lA = As + t * 8;
    __hip_bfloat16* lB = Bs + t * 8;

    f32x4 acc[4][4];
#pragma unroll
    for (int mi = 0; mi < 4; ++mi)
#pragma unroll
        for (int ni = 0; ni < 4; ++ni) {
            acc[mi][ni][0] = 0.f; acc[mi][ni][1] = 0.f;
            acc[mi][ni][2] = 0.f; acc[mi][ni][3] = 0.f;
        }

    for (int k0 = 0; k0 < K; k0 += 64) {
        __syncthreads();                 // previous tile's readers done
        load_lds16(gA,            lA);
        load_lds16(gA + 32 * lda, lA + 2048);
        load_lds16(gA + 64 * lda, lA + 4096);
        load_lds16(gA + 96 * lda, lA + 6144);
        load_lds16(gB,            lB);
        load_lds16(gB + 32 * K,   lB + 2048);
        load_lds16(gB + 64 * K,   lB + 4096);
        load_lds16(gB + 96 * K,   lB + 6144);
        gA += 64; gB += 64;
        __syncthreads();                 // staging drained (vmcnt(0) at barrier)

#pragma unroll
        for (int ks = 0; ks < 2; ++ks) {
            short8 af[4], bf_[4];
            const int u = ((ks * 4 + quad) ^ swz) * 8;   // swizzled unit offset
#pragma unroll
            for (int mi = 0; mi < 4; ++mi)
                af[mi] = *(const short8*)&As[(wm * 64 + mi * 16 + l15) * 64 + u];
#pragma unroll
            for (int ni = 0; ni < 4; ++ni)
                bf_[ni] = *(const short8*)&Bs[(wn * 64 + ni * 16 + l15) * 64 + u];
#pragma unroll
            for (int mi = 0; mi < 4; ++mi)
#pragma unroll
                for (int ni = 0; ni < 4; ++ni)
                    acc[mi][ni] = __builtin_amdgcn_mfma_f32_16x16x32_bf16(
                        af[mi], bf_[ni], acc[mi][ni], 0, 0, 0);
        }
    }

    // epilogue: C/D layout col = l15, row = quad*4 + reg
#pragma unroll
    for (int mi = 0; mi < 4; ++mi) {
        const int rowb = m0 + wm * 64 + mi * 16 + quad * 4;
#pragma unroll
        for (int ni = 0; ni < 4; ++ni) {
            const int col = n0 + wn * 64 + ni * 16 + l15;
#pragma unroll
            for (int r = 0; r < 4; ++r) {
                const size_t idx = (size_t)(rowb + r) * ldc + col;
                if (WRITE_BF16) {
                    float v = acc[mi][ni][r];
                    if (QSCALE && n0 < CC) v *= SC2F;   // fold softmax scale into Q
                    ((__hip_bfloat16*)Cout)[idx] = __float2bfloat16(v);
                } else {
                    ((float*)Cout)[idx] = acc[mi][ni][r] + bias[col];
                }
            }
        }
    }
}

// ---------------------------------------------------------------------------
// Flash attention, QBLK=128 x 8 waves (scale-up of the R6-proven loop):
// per-wave work/fragments/swizzles unchanged; each block now computes 128
// q-rows per staged K/V tile -> stage-issue:compute ratio halves, K/V L2
// re-reads halve, and LDS 40 KB x 512 thr -> 4 blk/CU = 32 waves/CU (full).
// Ks single-buffered + mid-barrier; Vs double-buffered; staging issued
// after QK^T (latency hides under softmax+PV). Max-free softmax via native
// __expf; conflict-free XOR-swizzled LDS; per-wave P tile; setprio;
// XCD swizzle for K/V L2 residency.
// ---------------------------------------------------------------------------
__global__ __launch_bounds__(512, 4) void attn_mfma_kernel(
    const __hip_bfloat16* qkv,
    const __hip_bfloat16* __restrict__ vt,
    __hip_bfloat16* ao)                  // = qkv + 2*CC (V-column base)
{
    __shared__ __hip_bfloat16 Ks[64 * 64];      // 8 KB, single
    __shared__ __hip_bfloat16 Vs[2][64 * 64];   // 16 KB, double
    __shared__ short Pl[8 * 16 * 64];           // 16 KB, per-wave

    const int t    = threadIdx.x;
    const int l15  = t & 15;
    const int quad = (t >> 4) & 3;
    const int w    = t >> 6;        // 0..7
    const int swz  = l15 & 7;

    // XCD swizzle: each XCD owns 24 (b,h) pairs with all 8 q-tiles ->
    // K/VT panels (~320 KB/pair) L2-resident per XCD.
    const int L    = blockIdx.x + 8 * (blockIdx.y + 12 * blockIdx.z);
    const int g    = L & 7, s = L >> 3;          // nwg = 1536 = 8*192
    const int pair = g * 24 + (s >> 3);
    const int qt   = s & 7;
    const int h    = pair % 12;
    const int b    = pair / 12;

    const size_t rowbase = (size_t)b * N1;
    const __hip_bfloat16* qb  = qkv + rowbase * N_QKV + h * DH;
    const __hip_bfloat16* kb  = qkv + rowbase * N_QKV + CC + h * DH;
    const __hip_bfloat16* vtb = vt + (size_t)(b * HH + h) * 64 * KP;

    // staging: 512 threads x 1 chunk of 16B = one 8 KB tile
    const int rA = t >> 3, uA = (t & 7) ^ (rA & 7);

#define KSTAGE(k0) \
    load_lds16(kb + (size_t)((k0) + rA) * N_QKV + uA * 8, (char*)Ks + t * 16)
#define VSTAGE(bi, k0) \
    load_lds16(vtb + (size_t)rA * KP + (k0) + uA * 8, (char*)&Vs[(bi)][0] + t * 16)

    short8 qf[2];
    {
        const size_t qrow = (size_t)(qt * 128 + w * 16 + l15);
#pragma unroll
        for (int ks = 0; ks < 2; ++ks)
            qf[ks] = *(const short8*)(qb + qrow * N_QKV + ks * 32 + quad * 8);
    }

    f32x4 oac[4];
#pragma unroll
    for (int dt = 0; dt < 4; ++dt) {
        oac[dt][0] = 0.f; oac[dt][1] = 0.f; oac[dt][2] = 0.f; oac[dt][3] = 0.f;
    }
    float lrun = 0.f;
    short* Pw = Pl + (w * 16) * 64;

    // prologue: stage tile 0 (K and V), drain, barrier
    KSTAGE(0);
    VSTAGE(0, 0);
    __syncthreads();

    int cur = 0;
    for (int k0 = 0; k0 < N1; k0 += 64) {
        // ---- read K fragments to regs, QK^T (register-only) ----
        short8 kf[4][2];
#pragma unroll
        for (int mt = 0; mt < 4; ++mt)
#pragma unroll
            for (int ks = 0; ks < 2; ++ks)
                kf[mt][ks] = *(const short8*)
                    &Ks[(mt * 16 + l15) * 64 + ((4 * ks + quad) ^ swz) * 8];

        f32x4 st[4];
#pragma unroll
        for (int mt = 0; mt < 4; ++mt) {
            st[mt][0] = 0.f; st[mt][1] = 0.f; st[mt][2] = 0.f; st[mt][3] = 0.f;
        }
        __builtin_amdgcn_s_setprio(1);
#pragma unroll
        for (int ks = 0; ks < 2; ++ks)
#pragma unroll
            for (int mt = 0; mt < 4; ++mt)
                st[mt] = __builtin_amdgcn_mfma_f32_16x16x32_bf16(
                    kf[mt][ks], qf[ks], st[mt], 0, 0, 0);
        __builtin_amdgcn_s_setprio(0);

        // ---- mid-barrier: all waves done reading Ks (no vmem outstanding) ----
        __syncthreads();

        // ---- issue next tile's staging; latency hides under softmax+PV ----
        if (k0 + 64 < N1) {
            KSTAGE(k0 + 64);
            VSTAGE(cur ^ 1, k0 + 64);
        }

        // ---- max-free softmax: scale folded into Q, exp args bounded ----
        if (k0 + 64 > N1) {              // mask padded keys (last iter only)
#pragma unroll
            for (int mt = 0; mt < 4; ++mt)
#pragma unroll
                for (int r = 0; r < 4; ++r)
                    if (k0 + mt * 16 + quad * 4 + r >= N1) st[mt][r] = -1e30f;
        }
        float rsum = 0.f;
#pragma unroll
        for (int mt = 0; mt < 4; ++mt)
#pragma unroll
            for (int r = 0; r < 4; ++r) {
                const float p = __expf(st[mt][r]);
                st[mt][r] = p;
                rsum += p;
            }
        rsum += __shfl_xor(rsum, 16);
        rsum += __shfl_xor(rsum, 32);
        lrun += rsum;

        // P -> per-wave swizzled LDS tile (8B writes, conflict-free)
#pragma unroll
        for (int mt = 0; mt < 4; ++mt) {
            union { unsigned long long u; __hip_bfloat16 hh[4]; } pk;
#pragma unroll
            for (int r = 0; r < 4; ++r) pk.hh[r] = __float2bfloat16(st[mt][r]);
            const int unit = (2 * mt + (quad >> 1)) ^ swz;
            *(unsigned long long*)&Pw[l15 * 64 + unit * 8 + (quad & 1) * 4] = pk.u;
        }

        __builtin_amdgcn_s_setprio(1);
#pragma unroll
        for (int ks = 0; ks < 2; ++ks) {
            const short8 pf = *(const short8*)
                &Pw[l15 * 64 + ((4 * ks + quad) ^ swz) * 8];
#pragma unroll
            for (int dt = 0; dt < 4; ++dt) {
                const short8 vf = *(const short8*)
                    &Vs[cur][(l15 + 16 * dt) * 64 + ((4 * ks + quad) ^ swz) * 8];
                oac[dt] = __builtin_amdgcn_mfma_f32_16x16x32_bf16(pf, vf, oac[dt], 0, 0, 0);
            }
        }
        __builtin_amdgcn_s_setprio(0);

        // end barrier: drains my staging -> buffers sealed for next iter
        __syncthreads();
        cur ^= 1;
    }
#undef KSTAGE
#undef VSTAGE

    const float li = 1.0f / lrun;
#pragma unroll
    for (int r = 0; r < 4; ++r) {
        const float ir = __shfl(li, quad * 4 + r);
        const int qrow = qt * 128 + w * 16 + quad * 4 + r;
        __hip_bfloat16* orow = ao + ((size_t)b * NN + qrow) * N_QKV + h * DH;
#pragma unroll
        for (int dt = 0; dt < 4; ++dt)
            orow[l15 + 16 * dt] = __float2bfloat16(oac[dt][r] * ir);
    }
}

// ---------------------------------------------------------------------------
extern "C" void kernel_launch(void* const* d_in, const int* in_sizes, int n_in,
                              void* d_out, int out_size, void* d_ws, size_t ws_size,
                              hipStream_t stream) {
    const float* x      = (const float*)d_in[0];
    const float* sct    = (const float*)d_in[1];
    const float* W_qkv  = (const float*)d_in[2];
    const float* W_proj = (const float*)d_in[3];
    const float* b_proj = (const float*)d_in[4];
    float* out = (float*)d_out;

    // ws layout (bytes), total 125.0 MB (R6-proven):
    //   [0, 30.08M):    xt bf16 [19584][768]  -> later reused as VT bf16
    //                   [192*64][1224] (identical size: 30,081,024 B)
    //   [30.08M, 120.3M): qkv bf16 [19584][2304]; attention output is written
    //                     into the (dead after transpose) V columns [1536..2304)
    //   then WT_qkv bf16 [2304][768], WT_proj bf16 [768][768]
    char* p = (char*)d_ws;
    __hip_bfloat16* xt      = (__hip_bfloat16*)p;
    __hip_bfloat16* vtg     = (__hip_bfloat16*)p;            // aliases xt (dead)
    __hip_bfloat16* qkv     = (__hip_bfloat16*)(p + (size_t)MPAD * CC * 2);
    __hip_bfloat16* WTqkv   = (__hip_bfloat16*)(p + (size_t)MPAD * CC * 2 + (size_t)MPAD * N_QKV * 2);
    __hip_bfloat16* WTproj  = WTqkv + (size_t)N_QKV * CC;
    __hip_bfloat16* ao      = qkv + 2 * CC;                  // attn out, stride N_QKV

    cast_all_kernel<<<XT_BLOCKS + WQ_BLOCKS + WP_BLOCKS, 256, 0, stream>>>(
        x, sct, W_qkv, W_proj, xt, WTqkv, WTproj);

    mfma_gemm_bt<true, true><<<dim3(N_QKV / 128, MPAD / 128), 256, 0, stream>>>(
        xt, WTqkv, qkv, nullptr, CC, CC, N_QKV);
    transpose_v_kernel<<<dim3((N1 + 63) / 64, HH, BB), 256, 0, stream>>>(qkv, vtg);
    attn_mfma_kernel<<<dim3(NN / 128, HH, BB), 512, 0, stream>>>(qkv, vtg, ao);
    mfma_gemm_bt<false, false><<<dim3(CC / 128, M_PROJ / 128), 256, 0, stream>>>(
        ao, WTproj, out, b_proj, N_QKV, CC, CC);
}